// Round 1
// baseline (654.100 us; speedup 1.0000x reference)
//
#include <hip/hip_runtime.h>
#include <hip/hip_bf16.h>
#include <stdint.h>

// ---------------------------------------------------------------------------
// AdaptiveDecision fused kernel, MI355X / gfx950
//
// Math (per row, B=32768, C=1024, CH=256):
//   h  = LN(x); d = h@Wd+bd; g = h@Wg+bg; h1 = d*sigmoid(g)
//   h1 = h1*dw_w + dw_b                      (folded into W1)
//   t  = gelu_tanh(h1@W1'+b1')
//   y  = t@Wcomb + bcomb                     (Wcomb = W2@Wv@Wo@Wu@(I+Wld@Wlu))
//   out= 0.5*y + 0.5*x
// LN folding: LN(x)@W = rs*(x@(g.*W)) - rs*mu*colsum(g.*W) + (b + ln_b@W)
// ---------------------------------------------------------------------------

typedef float f32x4 __attribute__((ext_vector_type(4)));
typedef __bf16 bf16x8 __attribute__((ext_vector_type(8)));
typedef unsigned short u16x8 __attribute__((ext_vector_type(8)));

#define LN_EPS 1e-5f

__device__ __forceinline__ unsigned short f2bf(float f) {
  unsigned int u = __float_as_uint(f);
  u += 0x7fffu + ((u >> 16) & 1u);          // RNE
  return (unsigned short)(u >> 16);
}

// ---------------------------------------------------------------------------
// Prep 1: pack Gd = ln_g.*Wd, Gg = ln_g.*Wg (K=1024,N=256) and W1' = dw_w.*W1
// (K=256,N=256) into bf16 MFMA-B fragment order:
//   P[((kc*NT + nt)*64 + lane)*8 + j] = W[kc*32 + (lane>>4)*8 + j][nt*16 + (lane&15)]
// ---------------------------------------------------------------------------
__global__ void k_pack1(const float* __restrict__ ln_g, const float* __restrict__ Wd,
                        const float* __restrict__ Wg, const float* __restrict__ dw_w,
                        const float* __restrict__ W1,
                        unsigned short* __restrict__ PGd, unsigned short* __restrict__ PGg,
                        unsigned short* __restrict__ PW1) {
  int p = blockIdx.x * 256 + threadIdx.x;
  if (p < 262144) {
    int j = p & 7, lane = (p >> 3) & 63, nt = (p >> 9) & 15, kc = p >> 13;
    int k = kc * 32 + (lane >> 4) * 8 + j;
    int n = nt * 16 + (lane & 15);
    float g = ln_g[k];
    PGd[p] = f2bf(g * Wd[k * 256 + n]);
    PGg[p] = f2bf(g * Wg[k * 256 + n]);
  } else {
    int q = p - 262144;  // < 65536
    int j = q & 7, lane = (q >> 3) & 63, nt = (q >> 9) & 15, kc = q >> 13;
    int k = kc * 32 + (lane >> 4) * 8 + j;
    int n = nt * 16 + (lane & 15);
    PW1[q] = f2bf(dw_w[k] * W1[k * 256 + n]);
  }
}

// ---------------------------------------------------------------------------
// Prep 2: column sums + folded bias vectors + full bias chain.
//  blk0: gdv = colsum(ln_g.*Wd), bdp = bd + ln_b@Wd
//  blk1: same for Wg
//  blk2: b1p = b1 + dw_b@W1
//  blk3: bcomb = bc3 + (bc3@Wld)@Wlu,  bc3 = ((b2@Wv+bv)@Wo+bo)@Wu+bu
// ---------------------------------------------------------------------------
__global__ void k_vecprep(const float* __restrict__ ln_g, const float* __restrict__ ln_b,
                          const float* __restrict__ Wd, const float* __restrict__ bd,
                          const float* __restrict__ Wg, const float* __restrict__ bg,
                          const float* __restrict__ dw_b, const float* __restrict__ W1,
                          const float* __restrict__ b1,
                          const float* __restrict__ b2, const float* __restrict__ Wv,
                          const float* __restrict__ bv,
                          const float* __restrict__ Wo, const float* __restrict__ bo,
                          const float* __restrict__ Wu, const float* __restrict__ bu,
                          const float* __restrict__ Wld, const float* __restrict__ Wlu,
                          float* __restrict__ gdv, float* __restrict__ ggv,
                          float* __restrict__ bdp, float* __restrict__ bgp,
                          float* __restrict__ b1p, float* __restrict__ bcomb) {
  int tid = threadIdx.x;
  int blk = blockIdx.x;
  if (blk < 2) {
    const float* W = (blk == 0) ? Wd : Wg;
    float s1 = 0.f, s2 = 0.f;
    for (int k = 0; k < 1024; ++k) {
      float w = W[k * 256 + tid];
      s1 += ln_g[k] * w;
      s2 += ln_b[k] * w;
    }
    if (blk == 0) { gdv[tid] = s1; bdp[tid] = bd[tid] + s2; }
    else          { ggv[tid] = s1; bgp[tid] = bg[tid] + s2; }
  } else if (blk == 2) {
    float s = 0.f;
    for (int k = 0; k < 256; ++k) s += dw_b[k] * W1[k * 256 + tid];
    b1p[tid] = b1[tid] + s;
  } else {
    __shared__ float bc1[256], bc2[256], bc3[1024], red[256], s16[16];
    float s = 0.f;
    for (int k = 0; k < 256; ++k) s += b2[k] * Wv[k * 256 + tid];
    bc1[tid] = s + bv[tid];
    __syncthreads();
    s = 0.f;
    for (int k = 0; k < 256; ++k) s += bc1[k] * Wo[k * 256 + tid];
    bc2[tid] = s + bo[tid];
    __syncthreads();
    for (int c = tid; c < 1024; c += 256) {
      s = 0.f;
      for (int k = 0; k < 256; ++k) s += bc2[k] * Wu[k * 1024 + c];
      bc3[c] = s + bu[c];
    }
    __syncthreads();
    {
      int r = tid & 15, part = tid >> 4;
      s = 0.f;
      for (int n = part * 64; n < part * 64 + 64; ++n) s += bc3[n] * Wld[n * 16 + r];
      red[tid] = s;
    }
    __syncthreads();
    if (tid < 16) {
      s = 0.f;
      for (int p2 = 0; p2 < 16; ++p2) s += red[p2 * 16 + tid];
      s16[tid] = s;
    }
    __syncthreads();
    for (int c = tid; c < 1024; c += 256) {
      s = bc3[c];
      #pragma unroll
      for (int r = 0; r < 16; ++r) s += s16[r] * Wlu[r * 1024 + c];
      bcomb[c] = s;
    }
  }
}

// ---------------------------------------------------------------------------
// Prep 3: small fp32 GEMM, M=256 (4 rows/block), K=256, N = 256 or 1024.
// C = A@B.  grid = (N/256, 64)
// ---------------------------------------------------------------------------
__global__ void k_gemm(const float* __restrict__ A, const float* __restrict__ Bm,
                       float* __restrict__ Cm, int N) {
  __shared__ float As[4][256];
  int tid = threadIdx.x;
  int col = blockIdx.x * 256 + tid;
  int r0 = blockIdx.y * 4;
  for (int i = tid; i < 1024; i += 256)
    As[i >> 8][i & 255] = A[(r0 + (i >> 8)) * 256 + (i & 255)];
  __syncthreads();
  float acc[4] = {0.f, 0.f, 0.f, 0.f};
  for (int k = 0; k < 256; k += 4) {
    float b0 = Bm[(size_t)(k + 0) * N + col];
    float b1v = Bm[(size_t)(k + 1) * N + col];
    float b2v = Bm[(size_t)(k + 2) * N + col];
    float b3v = Bm[(size_t)(k + 3) * N + col];
    #pragma unroll
    for (int r = 0; r < 4; ++r) {
      float4 a = *(const float4*)&As[r][k];
      acc[r] += a.x * b0 + a.y * b1v + a.z * b2v + a.w * b3v;
    }
  }
  #pragma unroll
  for (int r = 0; r < 4; ++r) Cm[(size_t)(r0 + r) * N + col] = acc[r];
}

// Prep 4: M4 = M3 @ Wld   (256x1024 @ 1024x16). one block per row.
__global__ void k_m4(const float* __restrict__ M3, const float* __restrict__ Wld,
                     float* __restrict__ M4) {
  __shared__ float red[256];
  int r = blockIdx.x, tid = threadIdx.x;
  int s_ = tid & 15, part = tid >> 4;
  float acc = 0.f;
  for (int n = part * 64; n < part * 64 + 64; ++n)
    acc += M3[(size_t)r * 1024 + n] * Wld[n * 16 + s_];
  red[tid] = acc;
  __syncthreads();
  if (tid < 16) {
    float s = 0.f;
    for (int p = 0; p < 16; ++p) s += red[p * 16 + tid];
    M4[r * 16 + tid] = s;
  }
}

// Prep 5: Wcomb = M3 + M4@Wlu, packed bf16 fragment order (K=256 kc<8, N=1024 nt<64)
__global__ void k_packwc(const float* __restrict__ M3, const float* __restrict__ M4,
                         const float* __restrict__ Wlu, unsigned short* __restrict__ PWc) {
  int p = blockIdx.x * 256 + threadIdx.x;  // < 262144
  int j = p & 7, lane = (p >> 3) & 63, nt = (p >> 9) & 63, kc = p >> 15;
  int k = kc * 32 + (lane >> 4) * 8 + j;
  int n = nt * 16 + (lane & 15);
  float v = M3[(size_t)k * 1024 + n];
  #pragma unroll
  for (int r = 0; r < 16; ++r) v += M4[k * 16 + r] * Wlu[r * 1024 + n];
  PWc[p] = f2bf(v);
}

// ---------------------------------------------------------------------------
// Main fused kernel. 512 blocks x 256 threads (4 waves), BM=64 rows/block.
// MFMA 16x16x32 bf16. Frag layouts (measured, m89/m120):
//   A[m=lane&15][k=(lane>>4)*8+j], B[k=(lane>>4)*8+j][n=lane&15],
//   D[row=(lane>>4)*4+r][col=lane&15]
// ---------------------------------------------------------------------------
__global__ __launch_bounds__(256, 2) void k_main(
    const float* __restrict__ x,
    const unsigned short* __restrict__ PGd, const unsigned short* __restrict__ PGg,
    const unsigned short* __restrict__ PW1, const unsigned short* __restrict__ PWc,
    const float* __restrict__ gdv, const float* __restrict__ ggv,
    const float* __restrict__ bdp, const float* __restrict__ bgp,
    const float* __restrict__ b1p, const float* __restrict__ bcomb,
    float* __restrict__ out) {
  __shared__ unsigned short XA[4 * 64 * 8];     // 4KB  A-frag staging (one k-chunk)
  __shared__ unsigned short HBUF[4 * 8 * 64 * 8]; // 32KB h1 (stage2 A), then t (stage3 A)
  __shared__ float SMS[512];                    // staging partial sums / sumsq
  __shared__ float MURS[128];                   // per-row mu, rs

  const int tid = threadIdx.x;
  const int w = tid >> 6;
  const int l = tid & 63;
  const int q = l >> 4;
  const int m15 = l & 15;
  const int row0 = blockIdx.x * 64;

  // per-wave column constants (cols 0..255 space: col = w*64 + i*16 + m15)
  float gdc[4], ggc[4], bdc[4], bgc[4], b1c[4];
  #pragma unroll
  for (int i = 0; i < 4; ++i) {
    int col = (w << 6) + (i << 4) + m15;
    gdc[i] = gdv[col]; ggc[i] = ggv[col];
    bdc[i] = bdp[col]; bgc[i] = bgp[col];
    b1c[i] = b1p[col];
  }

  // ---------------- stage 1: [64,1024] @ (Gd | Gg) -> [64, 2x256] -------------
  f32x4 accd[4][4], accg[4][4];
  const f32x4 zero4 = {0.f, 0.f, 0.f, 0.f};
  #pragma unroll
  for (int mt = 0; mt < 4; ++mt)
    #pragma unroll
    for (int i = 0; i < 4; ++i) { accd[mt][i] = zero4; accg[mt][i] = zero4; }

  const int srow = tid >> 2;       // 0..63 : staging row
  const int sseg = tid & 3;        // 0..3  : 8-col segment
  const float4* xv = (const float4*)(x + (size_t)(row0 + srow) * 1024) + sseg * 2;
  const int xaw = ((((srow >> 4) << 6) + (sseg << 4) + (srow & 15)) << 3);
  float ssum = 0.f, ssq = 0.f;

  for (int kc = 0; kc < 32; ++kc) {
    float4 v0 = xv[(size_t)kc * 8];
    float4 v1 = xv[(size_t)kc * 8 + 1];
    // B fragments direct global->VGPR (pre-packed, coalesced lane*16B)
    bf16x8 bdf[4], bgf[4];
    #pragma unroll
    for (int i = 0; i < 4; ++i) {
      size_t off = ((size_t)(kc * 16 + w * 4 + i) * 64 + l) * 8;
      bdf[i] = *(const bf16x8*)(PGd + off);
      bgf[i] = *(const bf16x8*)(PGg + off);
    }
    ssum += v0.x + v0.y + v0.z + v0.w + v1.x + v1.y + v1.z + v1.w;
    ssq += v0.x * v0.x + v0.y * v0.y + v0.z * v0.z + v0.w * v0.w
         + v1.x * v1.x + v1.y * v1.y + v1.z * v1.z + v1.w * v1.w;
    u16x8 hh;
    hh[0] = f2bf(v0.x); hh[1] = f2bf(v0.y); hh[2] = f2bf(v0.z); hh[3] = f2bf(v0.w);
    hh[4] = f2bf(v1.x); hh[5] = f2bf(v1.y); hh[6] = f2bf(v1.z); hh[7] = f2bf(v1.w);
    *(u16x8*)&XA[xaw] = hh;
    __syncthreads();
    bf16x8 af[4];
    #pragma unroll
    for (int mt = 0; mt < 4; ++mt) af[mt] = *(const bf16x8*)&XA[(mt * 64 + l) * 8];
    #pragma unroll
    for (int mt = 0; mt < 4; ++mt) {
      #pragma unroll
      for (int i = 0; i < 4; ++i) {
        accd[mt][i] = __builtin_amdgcn_mfma_f32_16x16x32_bf16(af[mt], bdf[i], accd[mt][i], 0, 0, 0);
        accg[mt][i] = __builtin_amdgcn_mfma_f32_16x16x32_bf16(af[mt], bgf[i], accg[mt][i], 0, 0, 0);
      }
    }
    __syncthreads();
  }

  // LN statistics (raw fp32 x), 4 partials per row
  SMS[tid] = ssum;
  SMS[256 + tid] = ssq;
  __syncthreads();
  if (tid < 64) {
    float s = SMS[tid * 4] + SMS[tid * 4 + 1] + SMS[tid * 4 + 2] + SMS[tid * 4 + 3];
    float sq = SMS[256 + tid * 4] + SMS[256 + tid * 4 + 1] + SMS[256 + tid * 4 + 2] + SMS[256 + tid * 4 + 3];
    float mu = s * (1.f / 1024.f);
    float var = sq * (1.f / 1024.f) - mu * mu;
    MURS[tid * 2] = mu;
    MURS[tid * 2 + 1] = rsqrtf(var + LN_EPS);
  }
  __syncthreads();

  // stage-1 epilogue: LN correction + GLU gate; write h1 bf16 to HBUF (A-frag order)
  #pragma unroll
  for (int i = 0; i < 4; ++i) {
    int col = (w << 6) + (i << 4) + m15;
    int kc2 = col >> 5, q2 = (col >> 3) & 3, j2 = col & 7;
    #pragma unroll
    for (int mt = 0; mt < 4; ++mt) {
      int base = ((mt * 8 + kc2) * 64 + q2 * 16) * 8 + j2;
      #pragma unroll
      for (int r = 0; r < 4; ++r) {
        int row = mt * 16 + q * 4 + r;
        float mu = MURS[row * 2], rs = MURS[row * 2 + 1];
        float pd = rs * (accd[mt][i][r] - mu * gdc[i]) + bdc[i];
        float pg = rs * (accg[mt][i][r] - mu * ggc[i]) + bgc[i];
        float hv = pd / (1.f + __expf(-pg));
        HBUF[base + (q * 4 + r) * 8] = f2bf(hv);
      }
    }
  }
  __syncthreads();

  // ---------------- stage 2: t = gelu(h1 @ W1' + b1') ------------------------
  f32x4 acc2[4][4];
  #pragma unroll
  for (int mt = 0; mt < 4; ++mt)
    #pragma unroll
    for (int i = 0; i < 4; ++i) acc2[mt][i] = zero4;
  for (int kc = 0; kc < 8; ++kc) {
    bf16x8 bf[4], af[4];
    #pragma unroll
    for (int i = 0; i < 4; ++i)
      bf[i] = *(const bf16x8*)(PW1 + ((size_t)(kc * 16 + w * 4 + i) * 64 + l) * 8);
    #pragma unroll
    for (int mt = 0; mt < 4; ++mt) af[mt] = *(const bf16x8*)&HBUF[((mt * 8 + kc) * 64 + l) * 8];
    #pragma unroll
    for (int mt = 0; mt < 4; ++mt)
      #pragma unroll
      for (int i = 0; i < 4; ++i)
        acc2[mt][i] = __builtin_amdgcn_mfma_f32_16x16x32_bf16(af[mt], bf[i], acc2[mt][i], 0, 0, 0);
  }
  __syncthreads();   // everyone done READING HBUF before overwriting it with t
  #pragma unroll
  for (int i = 0; i < 4; ++i) {
    int col = (w << 6) + (i << 4) + m15;
    int kc2 = col >> 5, q2 = (col >> 3) & 3, j2 = col & 7;
    #pragma unroll
    for (int mt = 0; mt < 4; ++mt) {
      int base = ((mt * 8 + kc2) * 64 + q2 * 16) * 8 + j2;
      #pragma unroll
      for (int r = 0; r < 4; ++r) {
        float v = acc2[mt][i][r] + b1c[i];
        // tanh-approx gelu (jax.nn.gelu default)
        float u = 0.7978845608f * (v + 0.044715f * v * v * v);
        float th = 1.f - 2.f / (1.f + __expf(2.f * u));
        HBUF[base + (q * 4 + r) * 8] = f2bf(0.5f * v * (1.f + th));
      }
    }
  }
  __syncthreads();

  // ---------------- stage 3: y = t @ Wcomb + bcomb; out = 0.5y + 0.5x --------
  for (int nc = 0; nc < 4; ++nc) {
    f32x4 acc3[4][4];
    #pragma unroll
    for (int mt = 0; mt < 4; ++mt)
      #pragma unroll
      for (int i = 0; i < 4; ++i) acc3[mt][i] = zero4;
    for (int kc = 0; kc < 8; ++kc) {
      bf16x8 bf[4], af[4];
      #pragma unroll
      for (int i = 0; i < 4; ++i) {
        int nt3 = nc * 16 + w * 4 + i;
        bf[i] = *(const bf16x8*)(PWc + ((size_t)(kc * 64 + nt3) * 64 + l) * 8);
      }
      #pragma unroll
      for (int mt = 0; mt < 4; ++mt) af[mt] = *(const bf16x8*)&HBUF[((mt * 8 + kc) * 64 + l) * 8];
      #pragma unroll
      for (int mt = 0; mt < 4; ++mt)
        #pragma unroll
        for (int i = 0; i < 4; ++i)
          acc3[mt][i] = __builtin_amdgcn_mfma_f32_16x16x32_bf16(af[mt], bf[i], acc3[mt][i], 0, 0, 0);
    }
    #pragma unroll
    for (int i = 0; i < 4; ++i) {
      int col = ((nc * 16 + w * 4 + i) << 4) + m15;   // 0..1023
      float bc = bcomb[col];
      #pragma unroll
      for (int mt = 0; mt < 4; ++mt) {
        #pragma unroll
        for (int r = 0; r < 4; ++r) {
          int row = row0 + mt * 16 + q * 4 + r;
          size_t gi = (size_t)row * 1024 + col;
          out[gi] = 0.5f * (acc3[mt][i][r] + bc) + 0.5f * x[gi];
        }
      }
    }
  }
}

// ---------------------------------------------------------------------------
extern "C" void kernel_launch(void* const* d_in, const int* in_sizes, int n_in,
                              void* d_out, int out_size, void* d_ws, size_t ws_size,
                              hipStream_t stream) {
  const float* x    = (const float*)d_in[0];
  const float* ln_g = (const float*)d_in[1];
  const float* ln_b = (const float*)d_in[2];
  const float* Wd   = (const float*)d_in[3];
  const float* bd   = (const float*)d_in[4];
  const float* Wg   = (const float*)d_in[5];
  const float* bg   = (const float*)d_in[6];
  const float* dw_w = (const float*)d_in[7];
  const float* dw_b = (const float*)d_in[8];
  const float* W1   = (const float*)d_in[9];
  const float* b1   = (const float*)d_in[10];
  const float* W2   = (const float*)d_in[11];
  const float* b2   = (const float*)d_in[12];
  // d_in[13..16] = Wq,bq,Wk,bk : dead code (softmax over 1 key == 1)
  const float* Wv   = (const float*)d_in[17];
  const float* bv   = (const float*)d_in[18];
  const float* Wo   = (const float*)d_in[19];
  const float* bo   = (const float*)d_in[20];
  const float* Wu   = (const float*)d_in[21];
  const float* bu   = (const float*)d_in[22];
  const float* Wld  = (const float*)d_in[23];
  const float* Wlu  = (const float*)d_in[24];
  float* out = (float*)d_out;

  char* ws = (char*)d_ws;
  unsigned short* PGd = (unsigned short*)(ws + 0);        // 512KB
  unsigned short* PGg = (unsigned short*)(ws + 524288);   // 512KB
  unsigned short* PW1 = (unsigned short*)(ws + 1048576);  // 128KB
  unsigned short* PWc = (unsigned short*)(ws + 1179648);  // 512KB
  float* gdv   = (float*)(ws + 1703936);
  float* ggv   = (float*)(ws + 1704960);
  float* bdp   = (float*)(ws + 1705984);
  float* bgp   = (float*)(ws + 1707008);
  float* b1p   = (float*)(ws + 1708032);
  float* bcomb = (float*)(ws + 1709056);
  float* T1    = (float*)(ws + 1713152);   // 256KB
  float* T2    = (float*)(ws + 1975296);   // 256KB
  float* M3    = (float*)(ws + 2237440);   // 1MB
  float* M4    = (float*)(ws + 3286016);   // 16KB ; total 3302400 B

  hipLaunchKernelGGL(k_pack1, dim3(1280), dim3(256), 0, stream,
                     ln_g, Wd, Wg, dw_w, W1, PGd, PGg, PW1);
  hipLaunchKernelGGL(k_vecprep, dim3(4), dim3(256), 0, stream,
                     ln_g, ln_b, Wd, bd, Wg, bg, dw_b, W1, b1,
                     b2, Wv, bv, Wo, bo, Wu, bu, Wld, Wlu,
                     gdv, ggv, bdp, bgp, b1p, bcomb);
  hipLaunchKernelGGL(k_gemm, dim3(1, 64), dim3(256), 0, stream, W2, Wv, T1, 256);
  hipLaunchKernelGGL(k_gemm, dim3(1, 64), dim3(256), 0, stream, T1, Wo, T2, 256);
  hipLaunchKernelGGL(k_gemm, dim3(4, 64), dim3(256), 0, stream, T2, Wu, M3, 1024);
  hipLaunchKernelGGL(k_m4, dim3(256), dim3(256), 0, stream, M3, Wld, M4);
  hipLaunchKernelGGL(k_packwc, dim3(1024), dim3(256), 0, stream, M3, M4, Wlu, PWc);
  hipLaunchKernelGGL(k_main, dim3(512), dim3(256), 0, stream,
                     x, PGd, PGg, PW1, PWc, gdv, ggv, bdp, bgp, b1p, bcomb, out);
}

// Round 2
// 529.129 us; speedup vs baseline: 1.2362x; 1.2362x over previous
//
#include <hip/hip_runtime.h>
#include <hip/hip_bf16.h>
#include <stdint.h>

// ---------------------------------------------------------------------------
// AdaptiveDecision fused kernel, MI355X / gfx950  (round 2)
//
// Math (per row, B=32768, C=1024, CH=256):
//   h  = LN(x); d = h@Wd+bd; g = h@Wg+bg; h1 = d*sigmoid(g)
//   h1 = h1*dw_w + dw_b                      (folded into W1)
//   t  = gelu_tanh(h1@W1'+b1')
//   y  = t@Wcomb + bcomb                     (Wcomb = W2@Wv@Wo@Wu@(I+Wld@Wlu))
//   out= 0.5*y + 0.5*x
// LN folding: LN(x)@W = rs*(x@(g.*W)) - rs*mu*colsum(g.*W) + (b + ln_b@W)
// Bias chain rides as row 256 of a 272-row A through the weight-chain GEMMs.
// ---------------------------------------------------------------------------

typedef float f32x4 __attribute__((ext_vector_type(4)));
typedef __bf16 bf16x8 __attribute__((ext_vector_type(8)));
typedef unsigned short u16x8 __attribute__((ext_vector_type(8)));
typedef unsigned short u16x4 __attribute__((ext_vector_type(4)));

#define LN_EPS 1e-5f

__device__ __forceinline__ unsigned short f2bf(float f) {
  unsigned int u = __float_as_uint(f);
  u += 0x7fffu + ((u >> 16) & 1u);          // RNE
  return (unsigned short)(u >> 16);
}

// barrier that does NOT drain vmcnt: LDS-visibility only. Keeps prefetched
// global loads in flight across the barrier (the __syncthreads vmcnt(0) drain
// was the round-1 stall).
__device__ __forceinline__ void bar_lds() {
  asm volatile("s_waitcnt lgkmcnt(0)\n\ts_barrier" ::: "memory");
}

// ---------------------------------------------------------------------------
// P1: all independent prep in one launch (138 blocks):
//  0-31  : pack ln_g.*Wd -> PGd (+ atomic colsums gdvA, bdA)
//  32-63 : pack ln_g.*Wg -> PGg (+ atomic colsums ggvA, bgA)
//  64-71 : pack dw_w.*W1 -> PW1
//  72-79 : pack Wv -> PWv ; 80-87: Wo -> PWo ; 88-119: Wu -> PWu (N=1024)
//  120   : b1p = b1 + dw_b@W1
//  121-137: build A0 = [W2; b2; zeros]  (272 x 256 fp32)
// Packed B-frag layout: P[((kc*NT+nt)*64+lane)*8+j] = W[kc*32+(lane>>4)*8+j][nt*16+(lane&15)]
// ---------------------------------------------------------------------------
__global__ __launch_bounds__(256) void k_prep1(
    const float* __restrict__ ln_g, const float* __restrict__ ln_b,
    const float* __restrict__ Wd, const float* __restrict__ Wg,
    const float* __restrict__ dw_w, const float* __restrict__ dw_b,
    const float* __restrict__ W1, const float* __restrict__ b1,
    const float* __restrict__ W2, const float* __restrict__ b2,
    const float* __restrict__ Wv, const float* __restrict__ Wo,
    const float* __restrict__ Wu,
    unsigned short* __restrict__ PGd, unsigned short* __restrict__ PGg,
    unsigned short* __restrict__ PW1, unsigned short* __restrict__ PWv,
    unsigned short* __restrict__ PWo, unsigned short* __restrict__ PWu,
    float* __restrict__ gdvA, float* __restrict__ ggvA,
    float* __restrict__ bdA, float* __restrict__ bgA,
    float* __restrict__ b1p, float* __restrict__ A0) {
  __shared__ float S[32][257];
  const int b = blockIdx.x, tid = threadIdx.x;

  if (b < 120) {
    const float* src; const float* scale = nullptr; unsigned short* dst;
    int N = 256, kc, NT = 16, nt0 = 0;
    bool csum = false; float* accg_ = nullptr; float* accb_ = nullptr;
    if (b < 32)      { src = Wd; scale = ln_g; dst = PGd; kc = b;      csum = true; accg_ = gdvA; accb_ = bdA; }
    else if (b < 64) { src = Wg; scale = ln_g; dst = PGg; kc = b - 32; csum = true; accg_ = ggvA; accb_ = bgA; }
    else if (b < 72) { src = W1; scale = dw_w; dst = PW1; kc = b - 64; }
    else if (b < 80) { src = Wv; dst = PWv; kc = b - 72; }
    else if (b < 88) { src = Wo; dst = PWo; kc = b - 80; }
    else { int idx = b - 88; kc = idx >> 2; nt0 = (idx & 3) * 16; src = Wu; dst = PWu; N = 1024; NT = 64; }
    const int n0 = nt0 * 16;
    float csg = 0.f, csb = 0.f;
    for (int r = 0; r < 32; ++r) {
      int k = kc * 32 + r;
      float raw = src[(size_t)k * N + n0 + tid];
      float v = scale ? scale[k] * raw : raw;
      S[r][tid] = v;
      if (csum) { csg += v; csb += ln_b[k] * raw; }
    }
    if (csum) { atomicAdd(&accg_[tid], csg); atomicAdd(&accb_[tid], csb); }
    __syncthreads();
    const int ntL = tid >> 4;
    #pragma unroll
    for (int c = 0; c < 4; ++c) {
      int lane = (tid * 4 + c) & 63;
      int kb = (lane >> 4) * 8, nl = ntL * 16 + (lane & 15);
      u16x8 o;
      #pragma unroll
      for (int j = 0; j < 8; ++j) o[j] = f2bf(S[kb + j][nl]);
      *(u16x8*)(dst + ((size_t)(kc * NT + nt0 + ntL) * 64 + lane) * 8) = o;
    }
  } else if (b == 120) {
    float s = 0.f;
    for (int k = 0; k < 256; ++k) s += dw_b[k] * W1[k * 256 + tid];
    b1p[tid] = b1[tid] + s;
  } else {
    int rb = b - 121;                       // 0..16
    for (int it = 0; it < 16; ++it) {
      int el = rb * 4096 + it * 256 + tid;  // < 272*256
      int row = el >> 8, col = el & 255;
      float v = (row < 256) ? W2[el] : ((row == 256) ? b2[col] : 0.f);
      A0[el] = v;
    }
  }
}

// ---------------------------------------------------------------------------
// Chain GEMM: C[272,N] = A[272,256] @ PB(packed bf16), bias added to row 256.
// grid (17, N/256), 256 threads (4 waves), 16 rows/block, MFMA 16x16x32.
// ---------------------------------------------------------------------------
__global__ __launch_bounds__(256) void k_gemm272(
    const float* __restrict__ A, const unsigned short* __restrict__ PB,
    float* __restrict__ C, const float* __restrict__ bias, int NT) {
  __shared__ unsigned short XA[512];
  const int tid = threadIdx.x;
  const int w = tid >> 6, l = tid & 63, q = l >> 4, m15 = l & 15;
  const int r0 = blockIdx.x * 16, ncg = blockIdx.y, N = NT * 16;

  const int srow = tid >> 4, kk = (tid & 15) * 2;
  const int xaidx = ((kk >> 3) * 16 + srow) * 8 + (kk & 7);
  const float* arow = A + (size_t)(r0 + srow) * 256 + kk;

  f32x4 acc[4];
  const f32x4 zero4 = {0.f, 0.f, 0.f, 0.f};
  #pragma unroll
  for (int i = 0; i < 4; ++i) acc[i] = zero4;

  for (int kc = 0; kc < 8; ++kc) {
    float2 v = *(const float2*)(arow + kc * 32);
    u16x4 hv; hv[0] = f2bf(v.x); hv[1] = f2bf(v.y); hv[2] = 0; hv[3] = 0;
    XA[xaidx] = hv[0]; XA[xaidx + 1] = hv[1];
    __syncthreads();
    bf16x8 af = *(const bf16x8*)&XA[l * 8];
    #pragma unroll
    for (int i = 0; i < 4; ++i) {
      bf16x8 bf = *(const bf16x8*)(PB + ((size_t)(kc * NT + ncg * 16 + w * 4 + i) * 64 + l) * 8);
      acc[i] = __builtin_amdgcn_mfma_f32_16x16x32_bf16(af, bf, acc[i], 0, 0, 0);
    }
    __syncthreads();
  }
  #pragma unroll
  for (int i = 0; i < 4; ++i) {
    int col = ncg * 256 + (w * 4 + i) * 16 + m15;
    #pragma unroll
    for (int r = 0; r < 4; ++r) {
      int grow = r0 + q * 4 + r;
      float v = acc[i][r];
      if (grow == 256) v += bias[col];
      C[(size_t)grow * N + col] = v;
    }
  }
}

// ---------------------------------------------------------------------------
// P6: PWc = pack_bf16(M3 + (M3@Wld)@Wlu) for rows 0..255 (blocks 0..7, 32-row
// slabs; per-slab M4 computed in-block). Block 8: bcomb = bc3 + (bc3@Wld)@Wlu.
// ---------------------------------------------------------------------------
__global__ __launch_bounds__(256) void k_packwc(
    const float* __restrict__ M3, const float* __restrict__ Wld,
    const float* __restrict__ Wlu, unsigned short* __restrict__ PWc,
    float* __restrict__ bcomb) {
  const int b = blockIdx.x, tid = threadIdx.x;
  if (b < 8) {
    __shared__ float M4L[32][16];
    __shared__ unsigned short T[32][1032];
    const int k0 = b * 32;
    // phase A: M4 slab = M3slab @ Wld   (2 dots of length 1024 per thread)
    #pragma unroll
    for (int p = 0; p < 2; ++p) {
      int t2 = tid + p * 256;
      int kL = t2 >> 4, rr = t2 & 15;
      const float* mrow = M3 + (size_t)(k0 + kL) * 1024;
      float s = 0.f;
      #pragma unroll 4
      for (int n = 0; n < 1024; ++n) s += mrow[n] * Wld[n * 16 + rr];
      M4L[kL][rr] = s;
    }
    __syncthreads();
    // phase B: T[r][n] = bf16(M3[r][n] + sum_s M4L[r][s]*Wlu[s][n])
    for (int r = 0; r < 32; ++r) {
      const float* mrow = M3 + (size_t)(k0 + r) * 1024;
      #pragma unroll
      for (int c = 0; c < 4; ++c) {
        int n = tid + c * 256;
        float v = mrow[n];
        #pragma unroll
        for (int s = 0; s < 16; ++s) v += M4L[r][s] * Wlu[s * 1024 + n];
        T[r][n] = f2bf(v);
      }
    }
    __syncthreads();
    // phase C: write packed frags (coalesced 16B stores)
    const int ntL = tid >> 2;
    #pragma unroll
    for (int c = 0; c < 16; ++c) {
      int lane = (tid & 3) * 16 + c;
      int kb = (lane >> 4) * 8, nl = ntL * 16 + (lane & 15);
      u16x8 o;
      #pragma unroll
      for (int j = 0; j < 8; ++j) o[j] = T[kb + j][nl];
      *(u16x8*)(PWc + ((size_t)(b * 64 + ntL) * 64 + lane) * 8) = o;
    }
  } else {
    __shared__ float red[256], s16[16];
    const float* bc3 = M3 + (size_t)256 * 1024;
    int part = tid >> 4, rr = tid & 15;
    float s = 0.f;
    for (int n = part * 64; n < part * 64 + 64; ++n) s += bc3[n] * Wld[n * 16 + rr];
    red[tid] = s;
    __syncthreads();
    if (tid < 16) {
      float t = 0.f;
      for (int p = 0; p < 16; ++p) t += red[p * 16 + tid];
      s16[tid] = t;
    }
    __syncthreads();
    #pragma unroll
    for (int c = 0; c < 4; ++c) {
      int n = tid + c * 256;
      float v = bc3[n];
      #pragma unroll
      for (int r = 0; r < 16; ++r) v += s16[r] * Wlu[r * 1024 + n];
      bcomb[n] = v;
    }
  }
}

// ---------------------------------------------------------------------------
// Main fused kernel. 512 blocks x 512 threads (8 waves), 64 rows/block.
// Frag layouts (verified round 1): A[m=lane&15][k=(lane>>4)*8+j],
// B[k=(lane>>4)*8+j][n=lane&15], D[row=(lane>>4)*4+r][col=lane&15]
// ---------------------------------------------------------------------------
__global__ __launch_bounds__(512, 4) void k_main(
    const float* __restrict__ x,
    const unsigned short* __restrict__ PGd, const unsigned short* __restrict__ PGg,
    const unsigned short* __restrict__ PW1, const unsigned short* __restrict__ PWc,
    const float* __restrict__ gdvA, const float* __restrict__ ggvA,
    const float* __restrict__ bdA, const float* __restrict__ bgA,
    const float* __restrict__ bd, const float* __restrict__ bg,
    const float* __restrict__ b1p, const float* __restrict__ bcomb,
    float* __restrict__ out) {
  __shared__ unsigned short XA[2][2048];       // 8KB  dbuf A-frag staging
  __shared__ unsigned short HBUF[16384];       // 32KB h1 / t as A-frags
  __shared__ float SMS[1024];                  // 4KB  LN partials
  __shared__ float MURS[128];                  // mu, rs per row
  __shared__ float OBUF[16 * 260];             // 16.6KB output staging tile

  const int tid = threadIdx.x;
  const int w = tid >> 6, l = tid & 63, q = l >> 4, m15 = l & 15;
  const int row0 = blockIdx.x * 64;

  float gdc[2], ggc[2], bdc[2], bgc[2], b1c[2];
  #pragma unroll
  for (int i = 0; i < 2; ++i) {
    int col = w * 32 + i * 16 + m15;
    gdc[i] = gdvA[col]; ggc[i] = ggvA[col];
    bdc[i] = bdA[col] + bd[col];
    bgc[i] = bgA[col] + bg[col];
    b1c[i] = b1p[col];
  }

  // ---------------- stage 1: [64,1024] @ (Gd|Gg) ------------------------------
  f32x4 accd[4][2], accg[4][2];
  const f32x4 zero4 = {0.f, 0.f, 0.f, 0.f};
  #pragma unroll
  for (int mt = 0; mt < 4; ++mt)
    #pragma unroll
    for (int i = 0; i < 2; ++i) { accd[mt][i] = zero4; accg[mt][i] = zero4; }

  const int srow = tid >> 3, sseg = tid & 7;
  const float* xrow = x + (size_t)(row0 + srow) * 1024 + sseg * 4;
  const int xaidx = (((srow >> 4) * 64 + (sseg >> 1) * 16 + (srow & 15)) << 3) + (sseg & 1) * 4;
  float ssum = 0.f, ssq = 0.f;

  float4 v = *(const float4*)xrow;
  for (int kc = 0; kc < 32; ++kc) {
    const int p = kc & 1;
    u16x4 hv; hv[0] = f2bf(v.x); hv[1] = f2bf(v.y); hv[2] = f2bf(v.z); hv[3] = f2bf(v.w);
    *(u16x4*)&XA[p][xaidx] = hv;
    ssum += v.x + v.y + v.z + v.w;
    ssq += v.x * v.x + v.y * v.y + v.z * v.z + v.w * v.w;
    if (kc < 31) v = *(const float4*)(xrow + (kc + 1) * 32);   // prefetch (survives bar_lds)
    bar_lds();
    bf16x8 fd[2], fg[2];
    #pragma unroll
    for (int i = 0; i < 2; ++i) {
      size_t off = ((size_t)(kc * 16 + w * 2 + i) * 64 + l) * 8;
      fd[i] = *(const bf16x8*)(PGd + off);
      fg[i] = *(const bf16x8*)(PGg + off);
    }
    #pragma unroll
    for (int mt = 0; mt < 4; ++mt) {
      bf16x8 af = *(const bf16x8*)&XA[p][(mt * 64 + l) * 8];
      #pragma unroll
      for (int i = 0; i < 2; ++i) {
        accd[mt][i] = __builtin_amdgcn_mfma_f32_16x16x32_bf16(af, fd[i], accd[mt][i], 0, 0, 0);
        accg[mt][i] = __builtin_amdgcn_mfma_f32_16x16x32_bf16(af, fg[i], accg[mt][i], 0, 0, 0);
      }
    }
  }

  // LN statistics (8 partials/row)
  SMS[tid] = ssum;
  SMS[512 + tid] = ssq;
  bar_lds();
  if (tid < 64) {
    float s = 0.f, sq = 0.f;
    #pragma unroll
    for (int p2 = 0; p2 < 8; ++p2) { s += SMS[tid * 8 + p2]; sq += SMS[512 + tid * 8 + p2]; }
    float mu = s * (1.f / 1024.f);
    float var = sq * (1.f / 1024.f) - mu * mu;
    MURS[tid * 2] = mu;
    MURS[tid * 2 + 1] = rsqrtf(var + LN_EPS);
  }
  bar_lds();

  // stage-1 epilogue: LN correction + GLU gate -> h1 bf16 in HBUF (A-frag order)
  #pragma unroll
  for (int i = 0; i < 2; ++i) {
    int cloc = i * 16 + m15;                 // col = w*32 + cloc ; kc2 = w
    int q2 = i * 2 + (m15 >> 3), j2 = m15 & 7;
    #pragma unroll
    for (int mt = 0; mt < 4; ++mt) {
      #pragma unroll
      for (int r = 0; r < 4; ++r) {
        int row = mt * 16 + q * 4 + r;
        float mu = MURS[row * 2], rs = MURS[row * 2 + 1];
        float pd = rs * (accd[mt][i][r] - mu * gdc[i]) + bdc[i];
        float pg = rs * (accg[mt][i][r] - mu * ggc[i]) + bgc[i];
        float hv = pd / (1.f + __expf(-pg));
        HBUF[((mt * 8 + w) * 64 + q2 * 16 + q * 4 + r) * 8 + j2] = f2bf(hv);
      }
    }
  }
  bar_lds();

  // ---------------- stage 2: t = gelu(h1 @ W1' + b1') ------------------------
  f32x4 acc2[4][2];
  #pragma unroll
  for (int mt = 0; mt < 4; ++mt)
    #pragma unroll
    for (int i = 0; i < 2; ++i) acc2[mt][i] = zero4;
  for (int kc = 0; kc < 8; ++kc) {
    bf16x8 bf[2];
    #pragma unroll
    for (int i = 0; i < 2; ++i)
      bf[i] = *(const bf16x8*)(PW1 + ((size_t)(kc * 16 + w * 2 + i) * 64 + l) * 8);
    #pragma unroll
    for (int mt = 0; mt < 4; ++mt) {
      bf16x8 af = *(const bf16x8*)&HBUF[((mt * 8 + kc) * 64 + l) * 8];
      #pragma unroll
      for (int i = 0; i < 2; ++i)
        acc2[mt][i] = __builtin_amdgcn_mfma_f32_16x16x32_bf16(af, bf[i], acc2[mt][i], 0, 0, 0);
    }
  }
  bar_lds();   // all reads of h1 done before overwrite with t
  #pragma unroll
  for (int i = 0; i < 2; ++i) {
    int q2 = i * 2 + (m15 >> 3), j2 = m15 & 7;
    #pragma unroll
    for (int mt = 0; mt < 4; ++mt) {
      #pragma unroll
      for (int r = 0; r < 4; ++r) {
        float vv = acc2[mt][i][r] + b1c[i];
        float u = 0.7978845608f * (vv + 0.044715f * vv * vv * vv);
        float th = 1.f - 2.f / (1.f + __expf(2.f * u));
        HBUF[((mt * 8 + w) * 64 + q2 * 16 + q * 4 + r) * 8 + j2] = f2bf(0.5f * vv * (1.f + th));
      }
    }
  }
  bar_lds();

  // ---------------- stage 3: y = t @ Wcomb + bcomb; out = 0.5y + 0.5x --------
  for (int nc = 0; nc < 4; ++nc) {
    f32x4 acc3[4][2];
    #pragma unroll
    for (int mt = 0; mt < 4; ++mt)
      #pragma unroll
      for (int i = 0; i < 2; ++i) acc3[mt][i] = zero4;
    for (int kc = 0; kc < 8; ++kc) {
      bf16x8 bf[2];
      #pragma unroll
      for (int i = 0; i < 2; ++i)
        bf[i] = *(const bf16x8*)(PWc + ((size_t)(kc * 64 + nc * 16 + w * 2 + i) * 64 + l) * 8);
      #pragma unroll
      for (int mt = 0; mt < 4; ++mt) {
        bf16x8 af = *(const bf16x8*)&HBUF[((mt * 8 + kc) * 64 + l) * 8];
        #pragma unroll
        for (int i = 0; i < 2; ++i)
          acc3[mt][i] = __builtin_amdgcn_mfma_f32_16x16x32_bf16(af, bf[i], acc3[mt][i], 0, 0, 0);
      }
    }
    float bc[2];
    #pragma unroll
    for (int i = 0; i < 2; ++i) bc[i] = bcomb[nc * 256 + w * 32 + i * 16 + m15];
    // stage through OBUF per 16-row tile for coalesced float4 out writes
    const int rowL = tid >> 5, c0 = (tid & 31) * 4;
    #pragma unroll
    for (int mt = 0; mt < 4; ++mt) {
      #pragma unroll
      for (int r = 0; r < 4; ++r)
        #pragma unroll
        for (int i = 0; i < 2; ++i)
          OBUF[(q * 4 + r) * 260 + w * 32 + i * 16 + m15] = acc3[mt][i][r] + bc[i];
      bar_lds();
      const size_t gbase = (size_t)(row0 + mt * 16 + rowL) * 1024 + nc * 256;
      #pragma unroll
      for (int h = 0; h < 2; ++h) {
        int cc = c0 + h * 128;
        f32x4 yv = *(const f32x4*)&OBUF[rowL * 260 + cc];
        float4 xr = *(const float4*)(x + gbase + cc);
        float4 o;
        o.x = 0.5f * yv[0] + 0.5f * xr.x;
        o.y = 0.5f * yv[1] + 0.5f * xr.y;
        o.z = 0.5f * yv[2] + 0.5f * xr.z;
        o.w = 0.5f * yv[3] + 0.5f * xr.w;
        *(float4*)(out + gbase + cc) = o;
      }
      bar_lds();
    }
  }
}

// ---------------------------------------------------------------------------
extern "C" void kernel_launch(void* const* d_in, const int* in_sizes, int n_in,
                              void* d_out, int out_size, void* d_ws, size_t ws_size,
                              hipStream_t stream) {
  (void)in_sizes; (void)n_in; (void)out_size; (void)ws_size;
  const float* x    = (const float*)d_in[0];
  const float* ln_g = (const float*)d_in[1];
  const float* ln_b = (const float*)d_in[2];
  const float* Wd   = (const float*)d_in[3];
  const float* bd   = (const float*)d_in[4];
  const float* Wg   = (const float*)d_in[5];
  const float* bg   = (const float*)d_in[6];
  const float* dw_w = (const float*)d_in[7];
  const float* dw_b = (const float*)d_in[8];
  const float* W1   = (const float*)d_in[9];
  const float* b1   = (const float*)d_in[10];
  const float* W2   = (const float*)d_in[11];
  const float* b2   = (const float*)d_in[12];
  // d_in[13..16] = Wq,bq,Wk,bk : dead code (softmax over 1 key == 1)
  const float* Wv   = (const float*)d_in[17];
  const float* bv   = (const float*)d_in[18];
  const float* Wo   = (const float*)d_in[19];
  const float* bo   = (const float*)d_in[20];
  const float* Wu   = (const float*)d_in[21];
  const float* bu   = (const float*)d_in[22];
  const float* Wld  = (const float*)d_in[23];
  const float* Wlu  = (const float*)d_in[24];
  float* out = (float*)d_out;

  char* ws = (char*)d_ws;
  unsigned short* PGd = (unsigned short*)(ws + 0);         // 512KB
  unsigned short* PGg = (unsigned short*)(ws + 524288);    // 512KB
  unsigned short* PW1 = (unsigned short*)(ws + 1048576);   // 128KB
  unsigned short* PWv = (unsigned short*)(ws + 1179648);   // 128KB
  unsigned short* PWo = (unsigned short*)(ws + 1310720);   // 128KB
  unsigned short* PWu = (unsigned short*)(ws + 1441792);   // 512KB
  unsigned short* PWc = (unsigned short*)(ws + 1966080);   // 512KB
  float* gdvA  = (float*)(ws + 2490368);                   // 1KB (zeroed)
  float* ggvA  = (float*)(ws + 2491392);                   // 1KB (zeroed)
  float* bdA   = (float*)(ws + 2492416);                   // 1KB (zeroed)
  float* bgA   = (float*)(ws + 2493440);                   // 1KB (zeroed)
  float* b1p   = (float*)(ws + 2494464);                   // 1KB
  float* bcomb = (float*)(ws + 2495488);                   // 4KB
  float* A0    = (float*)(ws + 2499584);                   // 272x256 f32 (278528B)
  float* T1    = (float*)(ws + 2778112);                   // 272x256 f32
  float* T2    = A0;                                       // alias: A0 dead after P2
  float* M3    = T1;                                       // alias: T1 dead after P3
  // M3 is 272x1024 f32 = 1114112B @2778112 -> end 3892224

  hipMemsetAsync(ws + 2490368, 0, 4096, stream);
  hipLaunchKernelGGL(k_prep1, dim3(138), dim3(256), 0, stream,
                     ln_g, ln_b, Wd, Wg, dw_w, dw_b, W1, b1, W2, b2, Wv, Wo, Wu,
                     PGd, PGg, PW1, PWv, PWo, PWu, gdvA, ggvA, bdA, bgA, b1p, A0);
  hipLaunchKernelGGL(k_gemm272, dim3(17, 1), dim3(256), 0, stream, A0, PWv, T1, bv, 16);
  hipLaunchKernelGGL(k_gemm272, dim3(17, 1), dim3(256), 0, stream, T1, PWo, T2, bo, 16);
  hipLaunchKernelGGL(k_gemm272, dim3(17, 4), dim3(256), 0, stream, T2, PWu, M3, bu, 64);
  hipLaunchKernelGGL(k_packwc, dim3(9), dim3(256), 0, stream, M3, Wld, Wlu, PWc, bcomb);
  hipLaunchKernelGGL(k_main, dim3(512), dim3(512), 0, stream,
                     x, PGd, PGg, PW1, PWc, gdvA, ggvA, bdA, bgA, bd, bg, b1p, bcomb, out);
}